// Round 7
// baseline (850.469 us; speedup 1.0000x reference)
//
#include <hip/hip_runtime.h>

// LSTM (B=4096, T=512, IN=4, H=50) + final FC, MFMA v7: G-way group interleave.
// gates[200x16] = Wcat[200x64] @ [h;x][64x16], mfma_f32_16x16x32_bf16.
// k-layout: k=0..49 h (identity), x at k=56,58,60,62, rest zero A-cols.
// v7: ONE block of 8 waves advances G=4 INDEPENDENT 16-batch groups per
// barrier interval. R2-R6 showed a ~600cyc per-BARRIER serial chain/convoy
// cost invariant under TLP, LDS traffic, and global-load changes; G-interleave
// amortizes it 4x via in-stream ILP across independent groups. A-frags
// (weights) are loaded once and reused for all G groups.

#define HID  50
#define NROW 200
#define TT   512
#define NIN  4
#define BT   16
#define KD   72      // shorts per B-row (144B, 16B-aligned)
#define NW   8
#define G    4

typedef float f32x4 __attribute__((ext_vector_type(4)));
typedef short s16x8 __attribute__((ext_vector_type(8)));

__device__ __forceinline__ unsigned short f2bf(float f) {
    unsigned u = __builtin_bit_cast(unsigned, f);
    return (unsigned short)((u + 0x7FFF + ((u >> 16) & 1)) >> 16);
}
__device__ __forceinline__ float fast_sigmoid(float v) {
    float e = __builtin_amdgcn_exp2f(v * -1.442695040888963f);
    return __builtin_amdgcn_rcpf(1.0f + e);
}
__device__ __forceinline__ float fast_tanh(float v) {
    float e = __builtin_amdgcn_exp2f(v * -2.885390081777927f);
    return 2.0f * __builtin_amdgcn_rcpf(1.0f + e) - 1.0f;
}

// weight for interleaved A-row rowp (=4u+g) at k-position kp
__device__ __forceinline__ float wval(const float* W_hh, const float* W_ih,
                                      int rowp, int kp) {
    if (rowp >= NROW) return 0.0f;
    const int u = rowp >> 2, g = rowp & 3;
    if (kp < HID) return W_hh[(g * HID + u) * HID + kp];
    if (kp >= 56 && !(kp & 1)) return W_ih[(g * HID + u) * NIN + ((kp - 56) >> 1)];
    return 0.0f;
}

__global__ __launch_bounds__(64 * NW, 1)
void lstm_mfma7(const float* __restrict__ x,     // [B,T,4]
                const float* __restrict__ W_ih,  // [200,4]
                const float* __restrict__ W_hh,  // [200,50]
                const float* __restrict__ b_ih,  // [200]
                const float* __restrict__ b_hh,  // [200]
                const float* __restrict__ W_fc,  // [1,50]
                const float* __restrict__ b_fc,  // [1]
                float* __restrict__ out)         // [B,1]
{
    __shared__ __align__(16) unsigned short buf[G][2][BT][KD]; // [h;x] bf16, dbuf
    __shared__ float red[G * BT];

    const int tid = threadIdx.x;
    const int w   = tid >> 6;        // wave 0..7
    const int l   = tid & 63;
    const int lr  = l & 15;          // batch col / A row-in-tile
    const int lg  = l >> 4;          // k-group 0..3 / D row-group
    const int b0  = blockIdx.x * (BT * G);

    for (int i = tid; i < G * 2 * BT * KD; i += 64 * NW)
        ((unsigned short*)buf)[i] = 0;
    if (tid < G * BT) red[tid] = 0.0f;

    const bool two = (w < 5);
    const int  T0  = two ? w : (w + 5);   // waves 5,6,7 -> tiles 10,11,12
    const int  T1  = w + 5;               // valid only when two

    // ---- preload A fragments, bias, W_fc (once; shared by all G groups) ----
    s16x8 af0[2], af1[2];
    f32x4 bias0, bias1 = {0.f, 0.f, 0.f, 0.f};
    float wfc0 = 0.0f, wfc1 = 0.0f;
    {
        const int rowp = 16 * T0 + lr;
#pragma unroll
        for (int kh = 0; kh < 2; ++kh) {
            s16x8 f;
#pragma unroll
            for (int j = 0; j < 8; ++j)
                f[j] = (short)f2bf(wval(W_hh, W_ih, rowp, 32 * kh + 8 * lg + j));
            af0[kh] = f;
        }
#pragma unroll
        for (int r = 0; r < 4; ++r) {
            const int rr = 16 * T0 + 4 * lg + r;
            bias0[r] = (rr < NROW) ? (b_ih[(rr & 3) * HID + (rr >> 2)] +
                                      b_hh[(rr & 3) * HID + (rr >> 2)]) : 0.0f;
        }
        const int u = 4 * T0 + lg;
        wfc0 = (u < HID) ? W_fc[u] : 0.0f;
    }
    if (two) {
        const int rowp = 16 * T1 + lr;
#pragma unroll
        for (int kh = 0; kh < 2; ++kh) {
            s16x8 f;
#pragma unroll
            for (int j = 0; j < 8; ++j)
                f[j] = (short)f2bf(wval(W_hh, W_ih, rowp, 32 * kh + 8 * lg + j));
            af1[kh] = f;
        }
#pragma unroll
        for (int r = 0; r < 4; ++r) {
            const int rr = 16 * T1 + 4 * lg + r;
            bias1[r] = (rr < NROW) ? (b_ih[(rr & 3) * HID + (rr >> 2)] +
                                      b_hh[(rr & 3) * HID + (rr >> 2)]) : 0.0f;
        }
        const int u = 4 * T1 + lg;
        wfc1 = (u < HID) ? W_fc[u] : 0.0f;
    }
    __syncthreads();   // zeroed buf visible

    // x duty: waves 4..7 own group gx = w-4; lane (lg,lr) handles component lg
    // of batch (b0 + 16*gx + lr). One float per lane per step.
    const int gx = w & 3;
    const float* xgp = x + ((size_t)(b0 + 16 * gx + lr) * TT) * NIN + lg;
    if (w >= 4)   // seed x[t=0] into buf[gx][0], k = 56 + 2*lg
        buf[gx][0][lr][56 + 2 * lg] = f2bf(xgp[0]);
    __syncthreads();

    float c0[G], h0[G], c1[G], h1[G];
#pragma unroll
    for (int g = 0; g < G; ++g) { c0[g] = h0[g] = c1[g] = h1[g] = 0.f; }

    for (int t = 0; t < TT; ++t) {
        const int p = t & 1;

        // issue next-step x load early: full interval (~2000cyc) of latency cover
        float xv = 0.0f;
        const bool xduty = (w >= 4) && (t + 1 < TT);
        if (xduty) xv = xgp[(size_t)(t + 1) * NIN];

#pragma unroll
        for (int g = 0; g < G; ++g) {
            const s16x8 bf0v = *(const s16x8*)&buf[g][p][lr][8 * lg];
            const s16x8 bf1v = *(const s16x8*)&buf[g][p][lr][32 + 8 * lg];

            f32x4 a0 = __builtin_amdgcn_mfma_f32_16x16x32_bf16(af0[0], bf0v, bias0, 0, 0, 0);
            a0       = __builtin_amdgcn_mfma_f32_16x16x32_bf16(af0[1], bf1v, a0,    0, 0, 0);
            f32x4 a1;
            if (two) {
                a1 = __builtin_amdgcn_mfma_f32_16x16x32_bf16(af1[0], bf0v, bias1, 0, 0, 0);
                a1 = __builtin_amdgcn_mfma_f32_16x16x32_bf16(af1[1], bf1v, a1,    0, 0, 0);
            }

            {
                const float gi = fast_sigmoid(a0[0]);
                const float gf = fast_sigmoid(a0[1]);
                const float gg = fast_tanh(a0[2]);
                const float go = fast_sigmoid(a0[3]);
                c0[g] = gf * c0[g] + gi * gg;
                h0[g] = go * fast_tanh(c0[g]);
                buf[g][p ^ 1][lr][4 * T0 + lg] = f2bf(h0[g]);  // pad u: harmless
            }
            if (two) {
                const float gi = fast_sigmoid(a1[0]);
                const float gf = fast_sigmoid(a1[1]);
                const float gg = fast_tanh(a1[2]);
                const float go = fast_sigmoid(a1[3]);
                c1[g] = gf * c1[g] + gi * gg;
                h1[g] = go * fast_tanh(c1[g]);
                buf[g][p ^ 1][lr][4 * T1 + lg] = f2bf(h1[g]);
            }
        }

        if (xduty)   // vmcnt wait lands here, covered by the whole interval
            buf[gx][p ^ 1][lr][56 + 2 * lg] = f2bf(xv);

        __syncthreads();
    }

    // ---- FC epilogue: out[b] = sum_u W_fc[u]*h_T[u][b] + b_fc ----
#pragma unroll
    for (int g = 0; g < G; ++g) {
        float partial = wfc0 * h0[g] + wfc1 * h1[g];   // pad units: wfc==0
        partial += __shfl_down(partial, 32);
        partial += __shfl_down(partial, 16);
        if (l < BT) atomicAdd(&red[g * BT + l], partial);
    }
    __syncthreads();
    if (tid < G * BT) out[b0 + tid] = red[tid] + b_fc[0];
}

extern "C" void kernel_launch(void* const* d_in, const int* in_sizes, int n_in,
                              void* d_out, int out_size, void* d_ws, size_t ws_size,
                              hipStream_t stream) {
    const float* x    = (const float*)d_in[0];
    const float* W_ih = (const float*)d_in[1];
    const float* W_hh = (const float*)d_in[2];
    const float* b_ih = (const float*)d_in[3];
    const float* b_hh = (const float*)d_in[4];
    const float* W_fc = (const float*)d_in[5];
    const float* b_fc = (const float*)d_in[6];
    float* out        = (float*)d_out;

    const int B = in_sizes[0] / (TT * NIN);   // 4096
    lstm_mfma7<<<B / (BT * G), 64 * NW, 0, stream>>>(x, W_ih, W_hh, b_ih, b_hh,
                                                     W_fc, b_fc, out);
}